// Round 5
// baseline (3176.736 us; speedup 1.0000x reference)
//
#include <hip/hip_runtime.h>
#include <hip/hip_bf16.h>
#include <stdint.h>

typedef __attribute__((ext_vector_type(8))) short short8;
typedef __attribute__((ext_vector_type(4))) float f32x4;

#define LN_EPS 1e-5f
#define MFMA16(a, b, c) __builtin_amdgcn_mfma_f32_16x16x32_bf16(a, b, c, 0, 0, 0)

__device__ __forceinline__ ushort f2bf(float f) {
  union { float f; uint32_t u; } v; v.f = f;
  uint32_t u = v.u;
  return (ushort)((u + 0x7FFFu + ((u >> 16) & 1u)) >> 16);
}
__device__ __forceinline__ float bf2f(ushort b) {
  union { uint32_t u; float f; } v; v.u = ((uint32_t)b) << 16;
  return v.f;
}
__device__ __forceinline__ uint32_t cvtpk(float lo, float hi) {
  uint32_t r;
  asm volatile("v_cvt_pk_bf16_f32 %0, %1, %2" : "=v"(r) : "v"(lo), "v"(hi));
  return r;
}

// ---------------- fused prep: weight bf16-conversion + embed + deg ----------------

__global__ void zero_kernel(float* __restrict__ p, int n) {
  int i = blockIdx.x * 256 + threadIdx.x;
  if (i < n) p[i] = 0.f;
}

__global__ void prep_kernel(
    const float* __restrict__ x, const float* __restrict__ Win,
    const float* __restrict__ b_in, float* __restrict__ h, int N,
    const float* __restrict__ Wv, const float* __restrict__ Wo,
    const float* __restrict__ W1, const float* __restrict__ W2,
    ushort* __restrict__ Wvb, ushort* __restrict__ Wob,
    ushort* __restrict__ W1b, ushort* __restrict__ W2b,
    const int* __restrict__ ei, float* __restrict__ degf, int E,
    int convBlocks, int embedBlocks)
{
  int bid = blockIdx.x;
  if (bid < convBlocks) {
    int i = bid * 256 + threadIdx.x;
    if (i < 49152) { Wvb[i] = f2bf(Wv[i]); return; }
    i -= 49152;
    if (i < 49152) { Wob[i] = f2bf(Wo[i]); return; }
    i -= 49152;
    if (i < 786432) { W1b[i] = f2bf(W1[i]); return; }
    i -= 786432;
    if (i < 786432) W2b[i] = f2bf(W2[i]);
    return;
  }
  bid -= convBlocks;
  if (bid < embedBlocks) {
    int i = bid * 256 + threadIdx.x;
    if (i < N * 128) {
      int n = i >> 7, d = i & 127;
      float v = Win[d*3+0]*x[n*3+0] + Win[d*3+1]*x[n*3+1] + Win[d*3+2]*x[n*3+2] + b_in[d];
      h[i] = fmaxf(v, 0.f);
    }
    return;
  }
  bid -= embedBlocks;
  {
    int i = bid * 256 + threadIdx.x;
    int e0 = i * 4;
    if (e0 + 3 < E) {
      int4 c = *(const int4*)(ei + E + e0);
      atomicAdd(&degf[c.x], 1.0f); atomicAdd(&degf[c.y], 1.0f);
      atomicAdd(&degf[c.z], 1.0f); atomicAdd(&degf[c.w], 1.0f);
    } else {
      for (int e = e0; e < E; ++e) atomicAdd(&degf[ei[E + e]], 1.0f);
    }
  }
}

// ---------------- GCN tail kernels ----------------

__global__ void z_kernel(const float* __restrict__ h, const float* __restrict__ wd,
                         const float* __restrict__ bd, const float* __restrict__ degf,
                         float* __restrict__ u, int N) {
  int row = blockIdx.x * 4 + (threadIdx.x >> 6);
  int lane = threadIdx.x & 63;
  if (row >= N) return;
  const float* hr = h + (size_t)row * 128;
  float s = hr[lane] * wd[lane] + hr[64 + lane] * wd[64 + lane];
  #pragma unroll
  for (int o = 32; o >= 1; o >>= 1) s += __shfl_xor(s, o, 64);
  if (lane == 0) {
    float z = fmaxf(s + bd[0], 0.f);
    u[row] = z * rsqrtf(degf[row] + 1.0f);   // deg includes self-loop
  }
}

__global__ void scatter_kernel(const int* __restrict__ ei, const float* __restrict__ u,
                               float* __restrict__ t, int E) {
  int i = blockIdx.x * 256 + threadIdx.x;
  int e0 = i * 4;
  if (e0 + 3 < E) {
    int4 r = *(const int4*)(ei + e0);
    int4 c = *(const int4*)(ei + E + e0);
    atomicAdd(&t[c.x], u[r.x]); atomicAdd(&t[c.y], u[r.y]);
    atomicAdd(&t[c.z], u[r.z]); atomicAdd(&t[c.w], u[r.w]);
  } else {
    for (int e = e0; e < E; ++e) atomicAdd(&t[ei[E + e]], u[ei[e]]);
  }
}

__global__ void out_kernel(const float* __restrict__ degf, const float* __restrict__ u,
                           const float* __restrict__ t, const float* __restrict__ wg,
                           const float* __restrict__ bg, const float* __restrict__ wf,
                           const float* __restrict__ bfp, float* __restrict__ out, int N) {
  int n = blockIdx.x * 256 + threadIdx.x;
  if (n >= N) return;
  float dis = rsqrtf(degf[n] + 1.0f);
  float tf = dis * (t[n] + u[n]);
  float acc = bfp[0];
  #pragma unroll
  for (int j = 0; j < 32; ++j) acc += wf[j] * fmaxf(tf * wg[j] + bg[j], 0.f);
  out[n] = acc;
}

// ---------------- fused transformer layer ----------------
// 192-row tile, 384 thr (6 waves x 32 rows). LDS = hA 48KB (row-major swz) +
// wbuf 32KB (2x16KB dbuf, frag-major layout) = 80KB -> 2 blocks/CU, 12 waves/CU
// (3/SIMD via __launch_bounds__(384,3), VGPR<=170). FF: F=32 chunks (64 of them);
// h1 held in regs as B-frags -> chunk reads = 16 b128 (weights only), all
// frag-major contiguous 1KB reads (0 read conflicts). u stays in regs via
// swapped-operand uT = mfma(W1c, h1) + cvt_pk/shfl repack (verified r4).
// MFMA 16x16x32 bf16: A row=l&15,k=8*(l>>4)+j; B col=l&15; C/D col=l&15,row=4*(l>>4)+j.

__global__ __launch_bounds__(384, 3) void layer_kernel(
    float* __restrict__ h,
    const ushort* __restrict__ Wv, const ushort* __restrict__ Wo,
    const ushort* __restrict__ W1, const ushort* __restrict__ W2,
    const float* __restrict__ bv, const float* __restrict__ bo,
    const float* __restrict__ b1, const float* __restrict__ b2,
    const float* __restrict__ g1, const float* __restrict__ be1,
    const float* __restrict__ g2, const float* __restrict__ be2,
    int N)
{
  __shared__ ushort hA[192 * 128];   // 48KB, row stride 256B, swz byte ^= (row&7)<<4
  __shared__ ushort wbuf[16384];     // 32KB: attn = 2048 frag-units (Wv/Wo);
                                     // FF dbuf: [ch&1]*8192 us: W1c units 0-511, W2c 512-1023

  const int tid = threadIdx.x;
  const int lane = tid & 63;
  const int wave = tid >> 6;
  const int l15 = lane & 15;
  const int lg = lane >> 4;
  const int rowbase = blockIdx.x * 192;
  const int wrow = wave * 32;
  const int ssw = (l15 & 7) << 4;
  // frag-major read offset within a 64-unit block (ushort units):
  const int fswz = lg * 128 + ((l15 ^ (lg << 2)) << 3);

  // ---- stage h: fp32 global -> bf16 LDS (8 short8-units/thread) ----
  #pragma unroll
  for (int i = 0; i < 8; ++i) {
    int u = tid + i * 384;
    int row = u >> 4, k8 = u & 15;
    int g = rowbase + row;
    float4 f0 = make_float4(0.f, 0.f, 0.f, 0.f), f1 = f0;
    if (g < N) {
      const float4* p = (const float4*)(h + (size_t)g * 128 + k8 * 8);
      f0 = p[0]; f1 = p[1];
    }
    short8 v;
    v[0]=(short)f2bf(f0.x); v[1]=(short)f2bf(f0.y); v[2]=(short)f2bf(f0.z); v[3]=(short)f2bf(f0.w);
    v[4]=(short)f2bf(f1.x); v[5]=(short)f2bf(f1.y); v[6]=(short)f2bf(f1.z); v[7]=(short)f2bf(f1.w);
    *(short8*)((char*)hA + ((row << 8) + ((k8 << 4) ^ ((row & 7) << 4)))) = v;
  }
  // ---- stage Wv (frag-major, write-swizzled) ----
  #pragma unroll
  for (int i = 0; i < 6; ++i) {
    int u = tid + i * 384;
    if (u < 2048) {
      short8 v = *(const short8*)(Wv + u * 8);
      int col = u >> 4, k16 = u & 15;
      int unit = (((col >> 4) << 2) + (k16 >> 2)) * 64 + (k16 & 3) * 16 + ((col & 15) ^ ((k16 & 3) << 2));
      *(short8*)(wbuf + unit * 8) = v;
    }
  }
  __syncthreads();

  // prefetch Wo into regs (hidden under GEMM1)
  short8 wo[6];
  #pragma unroll
  for (int i = 0; i < 6; ++i) {
    int u = tid + i * 384;
    if (u < 2048) wo[i] = *(const short8*)(Wo + u * 8);
  }

  // ---- GEMM1: t = h @ Wv^T ----
  f32x4 tC[2][8];
  #pragma unroll
  for (int rt = 0; rt < 2; ++rt)
    #pragma unroll
    for (int ct = 0; ct < 8; ++ct) tC[rt][ct] = (f32x4){0.f, 0.f, 0.f, 0.f};
  __builtin_amdgcn_s_setprio(1);
  #pragma unroll
  for (int ks = 0; ks < 4; ++ks) {
    int asw = (ks * 64 + lg * 16) ^ ssw;
    short8 a0 = *(const short8*)((char*)hA + (((wrow + l15) << 8) + asw));
    short8 a1 = *(const short8*)((char*)hA + (((wrow + 16 + l15) << 8) + asw));
    #pragma unroll
    for (int ct = 0; ct < 8; ++ct) {
      short8 b = *(const short8*)(wbuf + (ct * 4 + ks) * 512 + fswz);
      tC[0][ct] = MFMA16(a0, b, tC[0][ct]);
      tC[1][ct] = MFMA16(a1, b, tC[1][ct]);
    }
  }
  __builtin_amdgcn_s_setprio(0);
  // t + bv -> hA (own rows only)
  #pragma unroll
  for (int ct = 0; ct < 8; ++ct) {
    int col = ct * 16 + l15;
    float bvv = bv[col];
    #pragma unroll
    for (int rt = 0; rt < 2; ++rt)
      #pragma unroll
      for (int j = 0; j < 4; ++j) {
        int lr = wrow + rt * 16 + lg * 4 + j;
        *(ushort*)((char*)hA + ((lr << 8) + ((col * 2) ^ ((lr & 7) << 4)))) =
            f2bf(tC[rt][ct][j] + bvv);
      }
  }
  __syncthreads();   // all Wv reads done
  // write Wo (frag-major)
  #pragma unroll
  for (int i = 0; i < 6; ++i) {
    int u = tid + i * 384;
    if (u < 2048) {
      int col = u >> 4, k16 = u & 15;
      int unit = (((col >> 4) << 2) + (k16 >> 2)) * 64 + (k16 & 3) * 16 + ((col & 15) ^ ((k16 & 3) << 2));
      *(short8*)(wbuf + unit * 8) = wo[i];
    }
  }
  __syncthreads();   // Wo ready

  // prefetch FF chunk0 into regs (hidden under GEMM2)
  short8 wr[3];
  {
    #pragma unroll
    for (int i = 0; i < 3; ++i) {
      int c = tid + i * 384;
      if (i < 2 || c < 1024)
        wr[i] = (c < 512) ? *(const short8*)(W1 + c * 8)
                          : *(const short8*)(W2 + (size_t)((c - 512) >> 2) * 2048 + ((c - 512) & 3) * 8);
    }
  }

  // ---- GEMM2: attn = t @ Wo^T ----
  #pragma unroll
  for (int rt = 0; rt < 2; ++rt)
    #pragma unroll
    for (int ct = 0; ct < 8; ++ct) tC[rt][ct] = (f32x4){0.f, 0.f, 0.f, 0.f};
  __builtin_amdgcn_s_setprio(1);
  #pragma unroll
  for (int ks = 0; ks < 4; ++ks) {
    int asw = (ks * 64 + lg * 16) ^ ssw;
    short8 a0 = *(const short8*)((char*)hA + (((wrow + l15) << 8) + asw));
    short8 a1 = *(const short8*)((char*)hA + (((wrow + 16 + l15) << 8) + asw));
    #pragma unroll
    for (int ct = 0; ct < 8; ++ct) {
      short8 b = *(const short8*)(wbuf + (ct * 4 + ks) * 512 + fswz);
      tC[0][ct] = MFMA16(a0, b, tC[0][ct]);
      tC[1][ct] = MFMA16(a1, b, tC[1][ct]);
    }
  }
  __builtin_amdgcn_s_setprio(0);

  // ---- residual1 (fp32 re-read of h) + bo, LN1 -> h1 (bf16) into hA ----
  float sum[2][4] = {{0,0,0,0},{0,0,0,0}};
  float sq[2][4]  = {{0,0,0,0},{0,0,0,0}};
  #pragma unroll
  for (int rt = 0; rt < 2; ++rt)
    #pragma unroll
    for (int ct = 0; ct < 8; ++ct) {
      float bov = bo[ct * 16 + l15];
      #pragma unroll
      for (int j = 0; j < 4; ++j) {
        int g = rowbase + wrow + rt * 16 + lg * 4 + j;
        float hv = (g < N) ? h[(size_t)g * 128 + ct * 16 + l15] : 0.f;
        float v = tC[rt][ct][j] + bov + hv;
        tC[rt][ct][j] = v;
        sum[rt][j] += v; sq[rt][j] += v * v;
      }
    }
  #pragma unroll
  for (int o = 1; o < 16; o <<= 1)
    #pragma unroll
    for (int rt = 0; rt < 2; ++rt)
      #pragma unroll
      for (int j = 0; j < 4; ++j) {
        sum[rt][j] += __shfl_xor(sum[rt][j], o, 64);
        sq[rt][j]  += __shfl_xor(sq[rt][j],  o, 64);
      }
  float mean[2][4], rstd[2][4];
  #pragma unroll
  for (int rt = 0; rt < 2; ++rt)
    #pragma unroll
    for (int j = 0; j < 4; ++j) {
      mean[rt][j] = sum[rt][j] * (1.f / 128.f);
      float var = sq[rt][j] * (1.f / 128.f) - mean[rt][j] * mean[rt][j];
      rstd[rt][j] = rsqrtf(var + LN_EPS);
    }
  #pragma unroll
  for (int ct = 0; ct < 8; ++ct) {
    int col = ct * 16 + l15;
    float g1v = g1[col], b1v = be1[col];
    #pragma unroll
    for (int rt = 0; rt < 2; ++rt)
      #pragma unroll
      for (int j = 0; j < 4; ++j) {
        int lr = wrow + rt * 16 + lg * 4 + j;
        float hh = (tC[rt][ct][j] - mean[rt][j]) * rstd[rt][j] * g1v + b1v;
        *(ushort*)((char*)hA + ((lr << 8) + ((col * 2) ^ ((lr & 7) << 4)))) = f2bf(hh);
      }
  }

  // ---- h1 B-frags into registers (wave-private rows; used for all 64 FF chunks) ----
  short8 h1B[2][4];
  #pragma unroll
  for (int rt = 0; rt < 2; ++rt)
    #pragma unroll
    for (int ks = 0; ks < 4; ++ks)
      h1B[rt][ks] = *(const short8*)((char*)hA +
          (((wrow + rt * 16 + l15) << 8) + ((ks * 64 + lg * 16) ^ ssw)));

  __syncthreads();   // all Wo reads done
  // write chunk0 -> buf0
  #pragma unroll
  for (int i = 0; i < 3; ++i) {
    int c = tid + i * 384;
    if (i < 2 || c < 1024) {
      int unit;
      if (c < 512) {
        int f = c >> 4, k16 = c & 15;
        unit = (((f >> 4) << 2) + (k16 >> 2)) * 64 + (k16 & 3) * 16 + ((f & 15) ^ ((k16 & 3) << 2));
      } else {
        int u2 = c - 512, d = u2 >> 2, fg = u2 & 3;
        unit = 512 + (d >> 4) * 64 + fg * 16 + ((d & 15) ^ (fg << 2));
      }
      *(short8*)(wbuf + unit * 8) = wr[i];
    }
  }
  // prefetch chunk1
  {
    const ushort* W1c = W1 + 32 * 128;
    const ushort* W2c = W2 + 32;
    #pragma unroll
    for (int i = 0; i < 3; ++i) {
      int c = tid + i * 384;
      if (i < 2 || c < 1024)
        wr[i] = (c < 512) ? *(const short8*)(W1c + c * 8)
                          : *(const short8*)(W2c + (size_t)((c - 512) >> 2) * 2048 + ((c - 512) & 3) * 8);
    }
  }
  __syncthreads();   // chunk0 ready

  // ---- FF: 64 chunks of F=32; u in regs; reads = weights only (16 b128/chunk) ----
  f32x4 acc[2][8];
  #pragma unroll
  for (int rt = 0; rt < 2; ++rt)
    #pragma unroll
    for (int ct = 0; ct < 8; ++ct) acc[rt][ct] = (f32x4){0.f, 0.f, 0.f, 0.f};

  for (int ch = 0; ch < 64; ++ch) {
    const int b16 = (ch & 1) << 13;   // buffer base in ushorts
    f32x4 uT[2][2];
    #pragma unroll
    for (int ft = 0; ft < 2; ++ft)
      #pragma unroll
      for (int rt = 0; rt < 2; ++rt) uT[ft][rt] = (f32x4){0.f, 0.f, 0.f, 0.f};
    __builtin_amdgcn_s_setprio(1);
    #pragma unroll
    for (int ks = 0; ks < 4; ++ks) {
      short8 aw0 = *(const short8*)(wbuf + b16 + (0 * 4 + ks) * 512 + fswz);
      short8 aw1 = *(const short8*)(wbuf + b16 + (1 * 4 + ks) * 512 + fswz);
      uT[0][0] = MFMA16(aw0, h1B[0][ks], uT[0][0]);
      uT[0][1] = MFMA16(aw0, h1B[1][ks], uT[0][1]);
      uT[1][0] = MFMA16(aw1, h1B[0][ks], uT[1][0]);
      uT[1][1] = MFMA16(aw1, h1B[1][ks], uT[1][1]);
    }
    __builtin_amdgcn_s_setprio(0);
    // bias + relu  (f = ch*32 + ft*16 + 4*lg + j)
    #pragma unroll
    for (int ft = 0; ft < 2; ++ft) {
      float4 b4 = *(const float4*)(b1 + ch * 32 + ft * 16 + lg * 4);
      #pragma unroll
      for (int rt = 0; rt < 2; ++rt) {
        uT[ft][rt][0] = fmaxf(uT[ft][rt][0] + b4.x, 0.f);
        uT[ft][rt][1] = fmaxf(uT[ft][rt][1] + b4.y, 0.f);
        uT[ft][rt][2] = fmaxf(uT[ft][rt][2] + b4.z, 0.f);
        uT[ft][rt][3] = fmaxf(uT[ft][rt][3] + b4.w, 0.f);
      }
    }
    // repack uT -> W2 A-frags (lane needs u[r=l15][f=8*lg+0..7])
    short8 fr[2];
    {
      const int s0 = l15 + ((lg & 1) << 5);
      const int s1 = s0 + 16;
      const bool hiq = (lg >= 2);
      #pragma unroll
      for (int rt = 0; rt < 2; ++rt) {
        uint32_t pA0 = cvtpk(uT[0][rt][0], uT[0][rt][1]);
        uint32_t pA1 = cvtpk(uT[0][rt][2], uT[0][rt][3]);
        uint32_t pB0 = cvtpk(uT[1][rt][0], uT[1][rt][1]);
        uint32_t pB1 = cvtpk(uT[1][rt][2], uT[1][rt][3]);
        uint32_t d0 = __shfl((int)pA0, s0, 64), d1 = __shfl((int)pA1, s0, 64);
        uint32_t d2 = __shfl((int)pA0, s1, 64), d3 = __shfl((int)pA1, s1, 64);
        uint32_t e0 = __shfl((int)pB0, s0, 64), e1 = __shfl((int)pB1, s0, 64);
        uint32_t e2 = __shfl((int)pB0, s1, 64), e3 = __shfl((int)pB1, s1, 64);
        union { uint32_t u[4]; short8 s; } f;
        f.u[0] = hiq ? e0 : d0; f.u[1] = hiq ? e1 : d1;
        f.u[2] = hiq ? e2 : d2; f.u[3] = hiq ? e3 : d3;
        fr[rt] = f.s;
      }
    }
    // acc += u @ W2c^T
    __builtin_amdgcn_s_setprio(1);
    #pragma unroll
    for (int ct = 0; ct < 8; ++ct) {
      short8 b = *(const short8*)(wbuf + b16 + 4096 + ct * 512 + fswz);
      acc[0][ct] = MFMA16(fr[0], b, acc[0][ct]);
      acc[1][ct] = MFMA16(fr[1], b, acc[1][ct]);
    }
    __builtin_amdgcn_s_setprio(0);

    if (ch < 63) {
      __syncthreads();   // chunk ch-1 readers of the other buffer are done
      const int nb16 = ((ch + 1) & 1) << 13;
      #pragma unroll
      for (int i = 0; i < 3; ++i) {
        int c = tid + i * 384;
        if (i < 2 || c < 1024) {
          int unit;
          if (c < 512) {
            int f = c >> 4, k16 = c & 15;
            unit = (((f >> 4) << 2) + (k16 >> 2)) * 64 + (k16 & 3) * 16 + ((f & 15) ^ ((k16 & 3) << 2));
          } else {
            int u2 = c - 512, d = u2 >> 2, fg = u2 & 3;
            unit = 512 + (d >> 4) * 64 + fg * 16 + ((d & 15) ^ (fg << 2));
          }
          *(short8*)(wbuf + nb16 + unit * 8) = wr[i];
        }
      }
      if (ch < 62) {
        const ushort* W1c = W1 + (size_t)(ch + 2) * 32 * 128;
        const ushort* W2c = W2 + (ch + 2) * 32;
        #pragma unroll
        for (int i = 0; i < 3; ++i) {
          int c = tid + i * 384;
          if (i < 2 || c < 1024)
            wr[i] = (c < 512) ? *(const short8*)(W1c + c * 8)
                              : *(const short8*)(W2c + (size_t)((c - 512) >> 2) * 2048 + ((c - 512) & 3) * 8);
        }
      }
      __syncthreads();   // next chunk ready
    }
  }

  // ---- residual2 (h1 from hA bf16) + b2, LN2 -> h (fp32 global) ----
  #pragma unroll
  for (int rt = 0; rt < 2; ++rt)
    #pragma unroll
    for (int j = 0; j < 4; ++j) { sum[rt][j] = 0.f; sq[rt][j] = 0.f; }
  #pragma unroll
  for (int rt = 0; rt < 2; ++rt)
    #pragma unroll
    for (int ct = 0; ct < 8; ++ct) {
      int col = ct * 16 + l15;
      float b2v = b2[col];
      #pragma unroll
      for (int j = 0; j < 4; ++j) {
        int lr = wrow + rt * 16 + lg * 4 + j;
        float h1v = bf2f(*(const ushort*)((char*)hA + ((lr << 8) + ((col * 2) ^ ((lr & 7) << 4)))));
        float v = acc[rt][ct][j] + b2v + h1v;
        acc[rt][ct][j] = v;
        sum[rt][j] += v; sq[rt][j] += v * v;
      }
    }
  #pragma unroll
  for (int o = 1; o < 16; o <<= 1)
    #pragma unroll
    for (int rt = 0; rt < 2; ++rt)
      #pragma unroll
      for (int j = 0; j < 4; ++j) {
        sum[rt][j] += __shfl_xor(sum[rt][j], o, 64);
        sq[rt][j]  += __shfl_xor(sq[rt][j],  o, 64);
      }
  #pragma unroll
  for (int rt = 0; rt < 2; ++rt)
    #pragma unroll
    for (int j = 0; j < 4; ++j) {
      mean[rt][j] = sum[rt][j] * (1.f / 128.f);
      float var = sq[rt][j] * (1.f / 128.f) - mean[rt][j] * mean[rt][j];
      rstd[rt][j] = rsqrtf(var + LN_EPS);
    }
  #pragma unroll
  for (int rt = 0; rt < 2; ++rt)
    #pragma unroll
    for (int ct = 0; ct < 8; ++ct) {
      int col = ct * 16 + l15;
      float g2v = g2[col], b2lv = be2[col];
      #pragma unroll
      for (int j = 0; j < 4; ++j) {
        int g = rowbase + wrow + rt * 16 + lg * 4 + j;
        if (g < N)
          h[(size_t)g * 128 + col] = (acc[rt][ct][j] - mean[rt][j]) * rstd[rt][j] * g2v + b2lv;
      }
    }
}

// ---------------- launcher ----------------

extern "C" void kernel_launch(void* const* d_in, const int* in_sizes, int n_in,
                              void* d_out, int out_size, void* d_ws, size_t ws_size,
                              hipStream_t stream) {
  const float* x   = (const float*)d_in[0];
  const int*   ei  = (const int*)d_in[1];
  const float* Win = (const float*)d_in[2];
  const float* b_in= (const float*)d_in[3];
  const float* Wv  = (const float*)d_in[4];
  const float* bv  = (const float*)d_in[5];
  const float* Wo  = (const float*)d_in[6];
  const float* bo  = (const float*)d_in[7];
  const float* W1  = (const float*)d_in[8];
  const float* b1  = (const float*)d_in[9];
  const float* W2  = (const float*)d_in[10];
  const float* b2  = (const float*)d_in[11];
  const float* ln1g= (const float*)d_in[12];
  const float* ln1b= (const float*)d_in[13];
  const float* ln2g= (const float*)d_in[14];
  const float* ln2b= (const float*)d_in[15];
  const float* Wd  = (const float*)d_in[16];
  const float* bd  = (const float*)d_in[17];
  const float* Wg  = (const float*)d_in[18];
  const float* bg  = (const float*)d_in[19];
  const float* Wf  = (const float*)d_in[20];
  const float* bfp = (const float*)d_in[21];

  const int N = in_sizes[0] / 3;
  const int E = in_sizes[1] / 2;

  char* ws = (char*)d_ws;
  float* h = (float*)ws;                     size_t off = (size_t)N * 128 * 4;
  ushort* Wvb = (ushort*)(ws + off);         off += (size_t)3 * 16384 * 2;
  ushort* Wob = (ushort*)(ws + off);         off += (size_t)3 * 16384 * 2;
  ushort* W1b = (ushort*)(ws + off);         off += (size_t)3 * 262144 * 2;
  ushort* W2b = (ushort*)(ws + off);         off += (size_t)3 * 262144 * 2;
  float* degf = (float*)(ws + off);          off += (size_t)N * 4;
  float* tarr = (float*)(ws + off);          off += (size_t)N * 4;
  float* uarr = (float*)(ws + off);          off += (size_t)N * 4;

  zero_kernel<<<(2 * N + 255) / 256, 256, 0, stream>>>(degf, 2 * N);  // degf + tarr adjacent

  const int convBlocks = 1671168 / 256;                 // 6528
  const int embedBlocks = (N * 128 + 255) / 256;
  const int degBlocks = ((E + 3) / 4 + 255) / 256;
  prep_kernel<<<convBlocks + embedBlocks + degBlocks, 256, 0, stream>>>(
      x, Win, b_in, h, N, Wv, Wo, W1, W2, Wvb, Wob, W1b, W2b,
      ei, degf, E, convBlocks, embedBlocks);

  const int grid = (N + 191) / 192;
  for (int l = 0; l < 3; ++l) {
    layer_kernel<<<grid, 384, 0, stream>>>(
        h,
        Wvb + (size_t)l * 16384, Wob + (size_t)l * 16384,
        W1b + (size_t)l * 262144, W2b + (size_t)l * 262144,
        bv + l * 128, bo + l * 128, b1 + l * 2048, b2 + l * 128,
        ln1g + l * 128, ln1b + l * 128, ln2g + l * 128, ln2b + l * 128,
        N);
  }

  z_kernel<<<(N + 3) / 4, 256, 0, stream>>>(h, Wd, bd, degf, uarr, N);
  scatter_kernel<<<((E + 3) / 4 + 255) / 256, 256, 0, stream>>>(ei, uarr, tarr, E);
  out_kernel<<<(N + 255) / 256, 256, 0, stream>>>(degf, uarr, tarr, Wg, bg, Wf, bfp,
                                                  (float*)d_out, N);
}

// Round 6
// 2063.129 us; speedup vs baseline: 1.5398x; 1.5398x over previous
//
#include <hip/hip_runtime.h>
#include <hip/hip_bf16.h>
#include <stdint.h>

typedef __attribute__((ext_vector_type(8))) short short8;
typedef __attribute__((ext_vector_type(4))) float f32x4;

#define LN_EPS 1e-5f
#define MFMA16(a, b, c) __builtin_amdgcn_mfma_f32_16x16x32_bf16(a, b, c, 0, 0, 0)

__device__ __forceinline__ ushort f2bf(float f) {
  union { float f; uint32_t u; } v; v.f = f;
  uint32_t u = v.u;
  return (ushort)((u + 0x7FFFu + ((u >> 16) & 1u)) >> 16);
}
__device__ __forceinline__ float bf2f(ushort b) {
  union { uint32_t u; float f; } v; v.u = ((uint32_t)b) << 16;
  return v.f;
}
__device__ __forceinline__ uint32_t cvtpk(float lo, float hi) {
  uint32_t r;
  asm volatile("v_cvt_pk_bf16_f32 %0, %1, %2" : "=v"(r) : "v"(lo), "v"(hi));
  return r;
}

// ---------------- prep: W1/W2 bf16 conv + Wc=Wo@Wv + bc=Wo@bv+bo + embed + deg ----------------

__global__ void zero_kernel(float* __restrict__ p, int n) {
  int i = blockIdx.x * 256 + threadIdx.x;
  if (i < n) p[i] = 0.f;
}

__global__ void prep_kernel(
    const float* __restrict__ x, const float* __restrict__ Win,
    const float* __restrict__ b_in, float* __restrict__ h, int N,
    const float* __restrict__ Wv, const float* __restrict__ bv,
    const float* __restrict__ Wo, const float* __restrict__ bo,
    const float* __restrict__ W1, const float* __restrict__ W2,
    ushort* __restrict__ W1b, ushort* __restrict__ W2b,
    ushort* __restrict__ Wcb, float* __restrict__ bcb,
    const int* __restrict__ ei, float* __restrict__ degf, int E,
    int convBlocks, int wcBlocks, int bcBlocks, int embedBlocks)
{
  int bid = blockIdx.x;
  if (bid < convBlocks) {
    int i = bid * 256 + threadIdx.x;
    if (i < 786432) { W1b[i] = f2bf(W1[i]); return; }
    i -= 786432;
    if (i < 786432) W2b[i] = f2bf(W2[i]);
    return;
  }
  bid -= convBlocks;
  if (bid < wcBlocks) {
    int idx = bid * 256 + threadIdx.x;     // < 49152
    int l = idx >> 14, rem = idx & 16383;
    int i = rem >> 7, m = rem & 127;
    const float* wo = Wo + l * 16384 + i * 128;
    const float* wv = Wv + l * 16384 + m;
    float acc = 0.f;
    #pragma unroll 8
    for (int k = 0; k < 128; ++k) acc += wo[k] * wv[(size_t)k * 128];
    Wcb[idx] = f2bf(acc);
    return;
  }
  bid -= wcBlocks;
  if (bid < bcBlocks) {
    int idx = bid * 256 + threadIdx.x;
    if (idx < 384) {
      int l = idx >> 7, i = idx & 127;
      const float* wo = Wo + l * 16384 + i * 128;
      const float* bvp = bv + l * 128;
      float acc = bo[l * 128 + i];
      #pragma unroll 8
      for (int k = 0; k < 128; ++k) acc += wo[k] * bvp[k];
      bcb[idx] = acc;
    }
    return;
  }
  bid -= bcBlocks;
  if (bid < embedBlocks) {
    int i = bid * 256 + threadIdx.x;
    if (i < N * 128) {
      int n = i >> 7, d = i & 127;
      float v = Win[d*3+0]*x[n*3+0] + Win[d*3+1]*x[n*3+1] + Win[d*3+2]*x[n*3+2] + b_in[d];
      h[i] = fmaxf(v, 0.f);
    }
    return;
  }
  bid -= embedBlocks;
  {
    int i = bid * 256 + threadIdx.x;
    int e0 = i * 4;
    if (e0 + 3 < E) {
      int4 c = *(const int4*)(ei + E + e0);
      atomicAdd(&degf[c.x], 1.0f); atomicAdd(&degf[c.y], 1.0f);
      atomicAdd(&degf[c.z], 1.0f); atomicAdd(&degf[c.w], 1.0f);
    } else {
      for (int e = e0; e < E; ++e) atomicAdd(&degf[ei[E + e]], 1.0f);
    }
  }
}

// ---------------- GCN tail kernels ----------------

__global__ void z_kernel(const float* __restrict__ h, const float* __restrict__ wd,
                         const float* __restrict__ bd, const float* __restrict__ degf,
                         float* __restrict__ u, int N) {
  int row = blockIdx.x * 4 + (threadIdx.x >> 6);
  int lane = threadIdx.x & 63;
  if (row >= N) return;
  const float* hr = h + (size_t)row * 128;
  float s = hr[lane] * wd[lane] + hr[64 + lane] * wd[64 + lane];
  #pragma unroll
  for (int o = 32; o >= 1; o >>= 1) s += __shfl_xor(s, o, 64);
  if (lane == 0) {
    float z = fmaxf(s + bd[0], 0.f);
    u[row] = z * rsqrtf(degf[row] + 1.0f);   // deg includes self-loop
  }
}

__global__ void scatter_kernel(const int* __restrict__ ei, const float* __restrict__ u,
                               float* __restrict__ t, int E) {
  int i = blockIdx.x * 256 + threadIdx.x;
  int e0 = i * 4;
  if (e0 + 3 < E) {
    int4 r = *(const int4*)(ei + e0);
    int4 c = *(const int4*)(ei + E + e0);
    atomicAdd(&t[c.x], u[r.x]); atomicAdd(&t[c.y], u[r.y]);
    atomicAdd(&t[c.z], u[r.z]); atomicAdd(&t[c.w], u[r.w]);
  } else {
    for (int e = e0; e < E; ++e) atomicAdd(&t[ei[E + e]], u[ei[e]]);
  }
}

__global__ void out_kernel(const float* __restrict__ degf, const float* __restrict__ u,
                           const float* __restrict__ t, const float* __restrict__ wg,
                           const float* __restrict__ bg, const float* __restrict__ wf,
                           const float* __restrict__ bfp, float* __restrict__ out, int N) {
  int n = blockIdx.x * 256 + threadIdx.x;
  if (n >= N) return;
  float dis = rsqrtf(degf[n] + 1.0f);
  float tf = dis * (t[n] + u[n]);
  float acc = bfp[0];
  #pragma unroll
  for (int j = 0; j < 32; ++j) acc += wf[j] * fmaxf(tf * wg[j] + bg[j], 0.f);
  out[n] = acc;
}

// ---------------- fused transformer layer ----------------
// 128-row tile, 256 thr (4 waves x 32 rows). LDS = hA 32KB + wbuf 32KB = 64KB
// -> 2 independent blocks/CU (8 waves/CU) for cross-block latency hiding.
// __launch_bounds__(256,2): VGPR cap 256 (observed hipcc rule cap=512/(ceil(wpb/4)*blocks))
// -> NO spill (live ~160). Attention folded: attn = h @ Wc^T + bc (Wc=Wo@Wv precomputed)
// -> single GEMM, no t intermediate. FF intermediate u in regs (swapped-operand
// uT + cvt_pk/shfl repack, verified r4/r5). 64 chunks of F=32, dbuf wbuf halves.
// MFMA 16x16x32 bf16: A/B row|col=l&15, k=8*(l>>4)+j; C/D col=l&15, row=4*(l>>4)+j.

__global__ __launch_bounds__(256, 2) void layer_kernel(
    float* __restrict__ h,
    const ushort* __restrict__ Wc,
    const ushort* __restrict__ W1, const ushort* __restrict__ W2,
    const float* __restrict__ bc,
    const float* __restrict__ b1, const float* __restrict__ b2,
    const float* __restrict__ g1, const float* __restrict__ be1,
    const float* __restrict__ g2, const float* __restrict__ be2,
    int N)
{
  __shared__ ushort hA[128 * 128];   // 32KB, row stride 256B, swz byte ^= (row&7)<<4
  __shared__ ushort wbuf[16384];     // 32KB: attn = Wc frag-major (2048 units);
                                     // FF dbuf halves 8192 us: W1c units 0-511, W2c 512-1023

  const int tid = threadIdx.x;
  const int lane = tid & 63;
  const int wave = tid >> 6;
  const int l15 = lane & 15;
  const int lg = lane >> 4;
  const int rowbase = blockIdx.x * 128;
  const int wrow = wave * 32;
  const int ssw = (l15 & 7) << 4;
  // frag-major read offset (ushort units): unit = lg*16 + (l15 ^ (lg<<2))
  const int fswz = lg * 128 + ((l15 ^ (lg << 2)) << 3);

  // ---- stage h (fp32 -> bf16, swz) + Wc (frag-major) ----
  #pragma unroll
  for (int i = 0; i < 8; ++i) {
    int u = tid + i * 256;            // 2048 short8 units of hA
    int row = u >> 4, k8 = u & 15;
    int g = rowbase + row;
    float4 f0 = make_float4(0.f, 0.f, 0.f, 0.f), f1 = f0;
    if (g < N) {
      const float4* p = (const float4*)(h + (size_t)g * 128 + k8 * 8);
      f0 = p[0]; f1 = p[1];
    }
    short8 v;
    v[0]=(short)f2bf(f0.x); v[1]=(short)f2bf(f0.y); v[2]=(short)f2bf(f0.z); v[3]=(short)f2bf(f0.w);
    v[4]=(short)f2bf(f1.x); v[5]=(short)f2bf(f1.y); v[6]=(short)f2bf(f1.z); v[7]=(short)f2bf(f1.w);
    *(short8*)((char*)hA + ((row << 8) + ((k8 << 4) ^ ((row & 7) << 4)))) = v;
  }
  #pragma unroll
  for (int i = 0; i < 8; ++i) {
    int u = tid + i * 256;            // 2048 units of Wc
    short8 v = *(const short8*)(Wc + u * 8);
    int col = u >> 4, k16 = u & 15;
    int unit = (((col >> 4) << 2) + (k16 >> 2)) * 64 + (k16 & 3) * 16 + ((col & 15) ^ ((k16 & 3) << 2));
    *(short8*)(wbuf + unit * 8) = v;
  }
  __syncthreads();

  // prefetch FF chunk0 (hidden under attn GEMM)
  short8 wr[4];
  #pragma unroll
  for (int i = 0; i < 4; ++i) {
    int c = tid + i * 256;
    wr[i] = (c < 512) ? *(const short8*)(W1 + c * 8)
                      : *(const short8*)(W2 + (size_t)((c - 512) >> 2) * 2048 + ((c - 512) & 3) * 8);
  }

  // ---- attn GEMM: a = h @ Wc^T ----
  f32x4 tC[2][8];
  #pragma unroll
  for (int rt = 0; rt < 2; ++rt)
    #pragma unroll
    for (int ct = 0; ct < 8; ++ct) tC[rt][ct] = (f32x4){0.f, 0.f, 0.f, 0.f};
  __builtin_amdgcn_s_setprio(1);
  #pragma unroll
  for (int ks = 0; ks < 4; ++ks) {
    int asw = (ks * 64 + lg * 16) ^ ssw;
    short8 a0 = *(const short8*)((char*)hA + (((wrow + l15) << 8) + asw));
    short8 a1 = *(const short8*)((char*)hA + (((wrow + 16 + l15) << 8) + asw));
    #pragma unroll
    for (int ct = 0; ct < 8; ++ct) {
      short8 b = *(const short8*)(wbuf + (ct * 4 + ks) * 512 + fswz);
      tC[0][ct] = MFMA16(a0, b, tC[0][ct]);
      tC[1][ct] = MFMA16(a1, b, tC[1][ct]);
    }
  }
  __builtin_amdgcn_s_setprio(0);

  // ---- residual1 (fp32 re-read of h) + bc, LN1 -> h1 (bf16) into hA ----
  float sum[2][4] = {{0,0,0,0},{0,0,0,0}};
  float sq[2][4]  = {{0,0,0,0},{0,0,0,0}};
  #pragma unroll
  for (int rt = 0; rt < 2; ++rt)
    #pragma unroll
    for (int ct = 0; ct < 8; ++ct) {
      float bcv = bc[ct * 16 + l15];
      #pragma unroll
      for (int j = 0; j < 4; ++j) {
        int g = rowbase + wrow + rt * 16 + lg * 4 + j;
        float hv = (g < N) ? h[(size_t)g * 128 + ct * 16 + l15] : 0.f;
        float v = tC[rt][ct][j] + bcv + hv;
        tC[rt][ct][j] = v;
        sum[rt][j] += v; sq[rt][j] += v * v;
      }
    }
  #pragma unroll
  for (int o = 1; o < 16; o <<= 1)
    #pragma unroll
    for (int rt = 0; rt < 2; ++rt)
      #pragma unroll
      for (int j = 0; j < 4; ++j) {
        sum[rt][j] += __shfl_xor(sum[rt][j], o, 64);
        sq[rt][j]  += __shfl_xor(sq[rt][j],  o, 64);
      }
  float mean[2][4], rstd[2][4];
  #pragma unroll
  for (int rt = 0; rt < 2; ++rt)
    #pragma unroll
    for (int j = 0; j < 4; ++j) {
      mean[rt][j] = sum[rt][j] * (1.f / 128.f);
      float var = sq[rt][j] * (1.f / 128.f) - mean[rt][j] * mean[rt][j];
      rstd[rt][j] = rsqrtf(var + LN_EPS);
    }
  #pragma unroll
  for (int ct = 0; ct < 8; ++ct) {
    int col = ct * 16 + l15;
    float g1v = g1[col], b1v = be1[col];
    #pragma unroll
    for (int rt = 0; rt < 2; ++rt)
      #pragma unroll
      for (int j = 0; j < 4; ++j) {
        int lr = wrow + rt * 16 + lg * 4 + j;
        float hh = (tC[rt][ct][j] - mean[rt][j]) * rstd[rt][j] * g1v + b1v;
        *(ushort*)((char*)hA + ((lr << 8) + ((col * 2) ^ ((lr & 7) << 4)))) = f2bf(hh);
      }
  }

  // ---- h1 B-frags into regs (own rows; used by all 64 FF chunks) ----
  short8 h1B[2][4];
  #pragma unroll
  for (int rt = 0; rt < 2; ++rt)
    #pragma unroll
    for (int ks = 0; ks < 4; ++ks)
      h1B[rt][ks] = *(const short8*)((char*)hA +
          (((wrow + rt * 16 + l15) << 8) + ((ks * 64 + lg * 16) ^ ssw)));

  __syncthreads();   // all Wc reads done -> wbuf reusable
  // write chunk0 -> half0
  #pragma unroll
  for (int i = 0; i < 4; ++i) {
    int c = tid + i * 256;
    int unit;
    if (c < 512) {
      int f = c >> 4, k16 = c & 15;
      unit = (((f >> 4) << 2) + (k16 >> 2)) * 64 + (k16 & 3) * 16 + ((f & 15) ^ ((k16 & 3) << 2));
    } else {
      int u2 = c - 512, d = u2 >> 2, fg = u2 & 3;
      unit = 512 + (d >> 4) * 64 + fg * 16 + ((d & 15) ^ (fg << 2));
    }
    *(short8*)(wbuf + unit * 8) = wr[i];
  }
  // prefetch chunk1
  {
    const ushort* W1c = W1 + 32 * 128;
    const ushort* W2c = W2 + 32;
    #pragma unroll
    for (int i = 0; i < 4; ++i) {
      int c = tid + i * 256;
      wr[i] = (c < 512) ? *(const short8*)(W1c + c * 8)
                        : *(const short8*)(W2c + (size_t)((c - 512) >> 2) * 2048 + ((c - 512) & 3) * 8);
    }
  }
  __syncthreads();   // chunk0 ready

  // ---- FF: 64 chunks of F=32; u in regs ----
  f32x4 acc[2][8];
  #pragma unroll
  for (int rt = 0; rt < 2; ++rt)
    #pragma unroll
    for (int ct = 0; ct < 8; ++ct) acc[rt][ct] = (f32x4){0.f, 0.f, 0.f, 0.f};

  for (int ch = 0; ch < 64; ++ch) {
    const int b16 = (ch & 1) << 13;
    f32x4 uT[2][2];
    #pragma unroll
    for (int ft = 0; ft < 2; ++ft)
      #pragma unroll
      for (int rt = 0; rt < 2; ++rt) uT[ft][rt] = (f32x4){0.f, 0.f, 0.f, 0.f};
    __builtin_amdgcn_s_setprio(1);
    #pragma unroll
    for (int ks = 0; ks < 4; ++ks) {
      short8 aw0 = *(const short8*)(wbuf + b16 + (0 * 4 + ks) * 512 + fswz);
      short8 aw1 = *(const short8*)(wbuf + b16 + (1 * 4 + ks) * 512 + fswz);
      uT[0][0] = MFMA16(aw0, h1B[0][ks], uT[0][0]);
      uT[0][1] = MFMA16(aw0, h1B[1][ks], uT[0][1]);
      uT[1][0] = MFMA16(aw1, h1B[0][ks], uT[1][0]);
      uT[1][1] = MFMA16(aw1, h1B[1][ks], uT[1][1]);
    }
    __builtin_amdgcn_s_setprio(0);
    // bias + relu  (f = ch*32 + ft*16 + 4*lg + j)
    #pragma unroll
    for (int ft = 0; ft < 2; ++ft) {
      float4 b4 = *(const float4*)(b1 + ch * 32 + ft * 16 + lg * 4);
      #pragma unroll
      for (int rt = 0; rt < 2; ++rt) {
        uT[ft][rt][0] = fmaxf(uT[ft][rt][0] + b4.x, 0.f);
        uT[ft][rt][1] = fmaxf(uT[ft][rt][1] + b4.y, 0.f);
        uT[ft][rt][2] = fmaxf(uT[ft][rt][2] + b4.z, 0.f);
        uT[ft][rt][3] = fmaxf(uT[ft][rt][3] + b4.w, 0.f);
      }
    }
    // repack uT -> W2 A-frags (lane needs u[r=l15][f=8*lg+0..7])
    short8 fr[2];
    {
      const int s0 = l15 + ((lg & 1) << 5);
      const int s1 = s0 + 16;
      const bool hiq = (lg >= 2);
      #pragma unroll
      for (int rt = 0; rt < 2; ++rt) {
        uint32_t pA0 = cvtpk(uT[0][rt][0], uT[0][rt][1]);
        uint32_t pA1 = cvtpk(uT[0][rt][2], uT[0][rt][3]);
        uint32_t pB0 = cvtpk(uT[1][rt][0], uT[1][rt][1]);
        uint32_t pB1 = cvtpk(uT[1][rt][2], uT[1][rt][3]);
        uint32_t d0 = __shfl((int)pA0, s0, 64), d1 = __shfl((int)pA1, s0, 64);
        uint32_t d2 = __shfl((int)pA0, s1, 64), d3 = __shfl((int)pA1, s1, 64);
        uint32_t e0 = __shfl((int)pB0, s0, 64), e1 = __shfl((int)pB1, s0, 64);
        uint32_t e2 = __shfl((int)pB0, s1, 64), e3 = __shfl((int)pB1, s1, 64);
        union { uint32_t u[4]; short8 s; } f;
        f.u[0] = hiq ? e0 : d0; f.u[1] = hiq ? e1 : d1;
        f.u[2] = hiq ? e2 : d2; f.u[3] = hiq ? e3 : d3;
        fr[rt] = f.s;
      }
    }
    // acc += u @ W2c^T
    __builtin_amdgcn_s_setprio(1);
    #pragma unroll
    for (int ct = 0; ct < 8; ++ct) {
      short8 b = *(const short8*)(wbuf + b16 + 4096 + ct * 512 + fswz);
      acc[0][ct] = MFMA16(fr[0], b, acc[0][ct]);
      acc[1][ct] = MFMA16(fr[1], b, acc[1][ct]);
    }
    __builtin_amdgcn_s_setprio(0);

    if (ch < 63) {
      __syncthreads();   // other-half readers done
      const int nb16 = ((ch + 1) & 1) << 13;
      #pragma unroll
      for (int i = 0; i < 4; ++i) {
        int c = tid + i * 256;
        int unit;
        if (c < 512) {
          int f = c >> 4, k16 = c & 15;
          unit = (((f >> 4) << 2) + (k16 >> 2)) * 64 + (k16 & 3) * 16 + ((f & 15) ^ ((k16 & 3) << 2));
        } else {
          int u2 = c - 512, d = u2 >> 2, fg = u2 & 3;
          unit = 512 + (d >> 4) * 64 + fg * 16 + ((d & 15) ^ (fg << 2));
        }
        *(short8*)(wbuf + nb16 + unit * 8) = wr[i];
      }
      if (ch < 62) {
        const ushort* W1c = W1 + (size_t)(ch + 2) * 32 * 128;
        const ushort* W2c = W2 + (ch + 2) * 32;
        #pragma unroll
        for (int i = 0; i < 4; ++i) {
          int c = tid + i * 256;
          wr[i] = (c < 512) ? *(const short8*)(W1c + c * 8)
                            : *(const short8*)(W2c + (size_t)((c - 512) >> 2) * 2048 + ((c - 512) & 3) * 8);
        }
      }
      __syncthreads();   // next chunk ready
    }
  }

  // ---- residual2 (h1 from hA bf16) + b2, LN2 -> h (fp32 global) ----
  #pragma unroll
  for (int rt = 0; rt < 2; ++rt)
    #pragma unroll
    for (int j = 0; j < 4; ++j) { sum[rt][j] = 0.f; sq[rt][j] = 0.f; }
  #pragma unroll
  for (int rt = 0; rt < 2; ++rt)
    #pragma unroll
    for (int ct = 0; ct < 8; ++ct) {
      int col = ct * 16 + l15;
      float b2v = b2[col];
      #pragma unroll
      for (int j = 0; j < 4; ++j) {
        int lr = wrow + rt * 16 + lg * 4 + j;
        float h1v = bf2f(*(const ushort*)((char*)hA + ((lr << 8) + ((col * 2) ^ ((lr & 7) << 4)))));
        float v = acc[rt][ct][j] + b2v + h1v;
        acc[rt][ct][j] = v;
        sum[rt][j] += v; sq[rt][j] += v * v;
      }
    }
  #pragma unroll
  for (int o = 1; o < 16; o <<= 1)
    #pragma unroll
    for (int rt = 0; rt < 2; ++rt)
      #pragma unroll
      for (int j = 0; j < 4; ++j) {
        sum[rt][j] += __shfl_xor(sum[rt][j], o, 64);
        sq[rt][j]  += __shfl_xor(sq[rt][j],  o, 64);
      }
  #pragma unroll
  for (int rt = 0; rt < 2; ++rt)
    #pragma unroll
    for (int j = 0; j < 4; ++j) {
      mean[rt][j] = sum[rt][j] * (1.f / 128.f);
      float var = sq[rt][j] * (1.f / 128.f) - mean[rt][j] * mean[rt][j];
      rstd[rt][j] = rsqrtf(var + LN_EPS);
    }
  #pragma unroll
  for (int rt = 0; rt < 2; ++rt)
    #pragma unroll
    for (int ct = 0; ct < 8; ++ct) {
      int col = ct * 16 + l15;
      float g2v = g2[col], b2lv = be2[col];
      #pragma unroll
      for (int j = 0; j < 4; ++j) {
        int g = rowbase + wrow + rt * 16 + lg * 4 + j;
        if (g < N)
          h[(size_t)g * 128 + col] = (acc[rt][ct][j] - mean[rt][j]) * rstd[rt][j] * g2v + b2lv;
      }
    }
}

// ---------------- launcher ----------------

extern "C" void kernel_launch(void* const* d_in, const int* in_sizes, int n_in,
                              void* d_out, int out_size, void* d_ws, size_t ws_size,
                              hipStream_t stream) {
  const float* x   = (const float*)d_in[0];
  const int*   ei  = (const int*)d_in[1];
  const float* Win = (const float*)d_in[2];
  const float* b_in= (const float*)d_in[3];
  const float* Wv  = (const float*)d_in[4];
  const float* bv  = (const float*)d_in[5];
  const float* Wo  = (const float*)d_in[6];
  const float* bo  = (const float*)d_in[7];
  const float* W1  = (const float*)d_in[8];
  const float* b1  = (const float*)d_in[9];
  const float* W2  = (const float*)d_in[10];
  const float* b2  = (const float*)d_in[11];
  const float* ln1g= (const float*)d_in[12];
  const float* ln1b= (const float*)d_in[13];
  const float* ln2g= (const float*)d_in[14];
  const float* ln2b= (const float*)d_in[15];
  const float* Wd  = (const float*)d_in[16];
  const float* bd  = (const float*)d_in[17];
  const float* Wg  = (const float*)d_in[18];
  const float* bg  = (const float*)d_in[19];
  const float* Wf  = (const float*)d_in[20];
  const float* bfp = (const float*)d_in[21];

  const int N = in_sizes[0] / 3;
  const int E = in_sizes[1] / 2;

  char* ws = (char*)d_ws;
  float* h = (float*)ws;                     size_t off = (size_t)N * 128 * 4;
  ushort* W1b = (ushort*)(ws + off);         off += (size_t)3 * 262144 * 2;
  ushort* W2b = (ushort*)(ws + off);         off += (size_t)3 * 262144 * 2;
  ushort* Wcb = (ushort*)(ws + off);         off += (size_t)3 * 16384 * 2;
  float* bcb  = (float*)(ws + off);          off += (size_t)384 * 4;
  float* degf = (float*)(ws + off);          off += (size_t)N * 4;
  float* tarr = (float*)(ws + off);          off += (size_t)N * 4;
  float* uarr = (float*)(ws + off);          off += (size_t)N * 4;

  zero_kernel<<<(2 * N + 255) / 256, 256, 0, stream>>>(degf, 2 * N);  // degf + tarr adjacent

  const int convBlocks = 2 * 786432 / 256;   // 6144
  const int wcBlocks = 49152 / 256;          // 192
  const int bcBlocks = 2;
  const int embedBlocks = (N * 128 + 255) / 256;
  const int degBlocks = ((E + 3) / 4 + 255) / 256;
  prep_kernel<<<convBlocks + wcBlocks + bcBlocks + embedBlocks + degBlocks, 256, 0, stream>>>(
      x, Win, b_in, h, N, Wv, bv, Wo, bo, W1, W2,
      W1b, W2b, Wcb, bcb, ei, degf, E,
      convBlocks, wcBlocks, bcBlocks, embedBlocks);

  const int grid = (N + 127) / 128;
  for (int l = 0; l < 3; ++l) {
    layer_kernel<<<grid, 256, 0, stream>>>(
        h,
        Wcb + (size_t)l * 16384,
        W1b + (size_t)l * 262144, W2b + (size_t)l * 262144,
        bcb + l * 128,
        b1 + l * 2048, b2 + l * 128,
        ln1g + l * 128, ln1b + l * 128, ln2g + l * 128, ln2b + l * 128,
        N);
  }

  z_kernel<<<(N + 3) / 4, 256, 0, stream>>>(h, Wd, bd, degf, uarr, N);
  scatter_kernel<<<((E + 3) / 4 + 255) / 256, 256, 0, stream>>>(ei, uarr, tarr, E);
  out_kernel<<<(N + 255) / 256, 256, 0, stream>>>(degf, uarr, tarr, Wg, bg, Wf, bfp,
                                                  (float*)d_out, N);
}